// Round 10
// baseline (1925.871 us; speedup 1.0000x reference)
//
#include <hip/hip_runtime.h>
#include <hip/hip_bf16.h>

#define B_ 32
#define T_ 2000
#define S_ 400
#define C0_ 80
#define H_ 256

static constexpr float NEGV = -1e9f;
static constexpr int NMU  = B_ * T_ * S_;       // 25,600,000
static constexpr int NPI  = 2 * NMU;            // 51,200,000

typedef _Float16 f16x8 __attribute__((ext_vector_type(8)));
typedef float    f32x4 __attribute__((ext_vector_type(4)));

// ---------------- weight repack: wcat[co][k*CPAD+ci] = w[k][ci][co] ------
__global__ __launch_bounds__(256)
void wprep(const float* __restrict__ w, _Float16* __restrict__ wcat,
           int CIN, int CPAD)
{
  const int tot = 256 * 5 * CPAD;
  int idx = blockIdx.x * 256 + threadIdx.x;
  if (idx >= tot) return;
  int co  = idx / (5 * CPAD);
  int rem = idx - co * (5 * CPAD);
  int k   = rem / CPAD;
  int ci  = rem - k * CPAD;
  float v = (ci < CIN) ? w[((size_t)k * CIN + ci) * H_ + co] : 0.f;
  wcat[idx] = (_Float16)v;
}

// ---------------- conv1d (K=5, SAME) + bias + tanh via f16 MFMA ----------
template<int CIN, int CPAD, bool INF32, bool OUTF32>
__global__ __launch_bounds__(256)
void conv_mfma(const void* __restrict__ xin, const _Float16* __restrict__ wcat,
               const float* __restrict__ bias, void* __restrict__ yout)
{
  constexpr int KK  = 5 * CPAD;      // 480 / 1280
  constexpr int NS  = KK / 32;       // 15 / 40
  constexpr int STR = CPAD + 8;      // LDS row stride
  __shared__ _Float16 xs[68 * STR];
  const int b   = blockIdx.y;
  const int t0  = blockIdx.x * 64;
  const int tid = threadIdx.x;
  const int w   = tid >> 6;
  const int l   = tid & 63;

  if constexpr (INF32) {
    const float* xb = (const float*)xin + (size_t)b * T_ * CIN;
    constexpr int NG = CPAD / 4;
    for (int idx = tid; idx < 68 * NG; idx += 256) {
      int j = idx / NG, g = idx - j * NG;
      int t = t0 - 2 + j;
      int c = g * 4;
      float4 v = make_float4(0.f, 0.f, 0.f, 0.f);
      if (t >= 0 && t < T_ && c < CIN) v = *(const float4*)&xb[(size_t)t * CIN + c];
      _Float16* d = &xs[j * STR + c];
      d[0] = (_Float16)v.x; d[1] = (_Float16)v.y;
      d[2] = (_Float16)v.z; d[3] = (_Float16)v.w;
    }
  } else {
    const _Float16* xb = (const _Float16*)xin + (size_t)b * T_ * CIN;
    constexpr int NG = CPAD / 8;
    for (int idx = tid; idx < 68 * NG; idx += 256) {
      int j = idx / NG, g = idx - j * NG;
      int t = t0 - 2 + j;
      f16x8 v = {(_Float16)0,(_Float16)0,(_Float16)0,(_Float16)0,
                 (_Float16)0,(_Float16)0,(_Float16)0,(_Float16)0};
      if (t >= 0 && t < T_) v = *(const f16x8*)&xb[(size_t)t * CIN + g * 8];
      *(f16x8*)&xs[j * STR + g * 8] = v;
    }
  }
  __syncthreads();

  const int lr = l & 15;
  const int lk = (l >> 4) * 8;

  f32x4 acc[4][4];
  const f32x4 zz = {0.f, 0.f, 0.f, 0.f};
#pragma unroll
  for (int i = 0; i < 4; i++)
#pragma unroll
    for (int j = 0; j < 4; j++) acc[i][j] = zz;

  const _Float16* wbase = wcat + (size_t)(w * 64 + lr) * KK + lk;

  for (int kk = 0; kk < NS; kk++) {
    const int p  = kk * 32;
    const int k  = p / CPAD;
    const int ci = p - k * CPAD;
    f16x8 a0 = *(const f16x8*)&xs[( 0 + lr + k) * STR + ci + lk];
    f16x8 a1 = *(const f16x8*)&xs[(16 + lr + k) * STR + ci + lk];
    f16x8 a2 = *(const f16x8*)&xs[(32 + lr + k) * STR + ci + lk];
    f16x8 a3 = *(const f16x8*)&xs[(48 + lr + k) * STR + ci + lk];
    f16x8 w0 = *(const f16x8*)&wbase[(size_t)( 0) * KK + p];
    f16x8 w1 = *(const f16x8*)&wbase[(size_t)(16) * KK + p];
    f16x8 w2 = *(const f16x8*)&wbase[(size_t)(32) * KK + p];
    f16x8 w3 = *(const f16x8*)&wbase[(size_t)(48) * KK + p];
    acc[0][0] = __builtin_amdgcn_mfma_f32_16x16x32_f16(a0, w0, acc[0][0], 0, 0, 0);
    acc[0][1] = __builtin_amdgcn_mfma_f32_16x16x32_f16(a0, w1, acc[0][1], 0, 0, 0);
    acc[0][2] = __builtin_amdgcn_mfma_f32_16x16x32_f16(a0, w2, acc[0][2], 0, 0, 0);
    acc[0][3] = __builtin_amdgcn_mfma_f32_16x16x32_f16(a0, w3, acc[0][3], 0, 0, 0);
    acc[1][0] = __builtin_amdgcn_mfma_f32_16x16x32_f16(a1, w0, acc[1][0], 0, 0, 0);
    acc[1][1] = __builtin_amdgcn_mfma_f32_16x16x32_f16(a1, w1, acc[1][1], 0, 0, 0);
    acc[1][2] = __builtin_amdgcn_mfma_f32_16x16x32_f16(a1, w2, acc[1][2], 0, 0, 0);
    acc[1][3] = __builtin_amdgcn_mfma_f32_16x16x32_f16(a1, w3, acc[1][3], 0, 0, 0);
    acc[2][0] = __builtin_amdgcn_mfma_f32_16x16x32_f16(a2, w0, acc[2][0], 0, 0, 0);
    acc[2][1] = __builtin_amdgcn_mfma_f32_16x16x32_f16(a2, w1, acc[2][1], 0, 0, 0);
    acc[2][2] = __builtin_amdgcn_mfma_f32_16x16x32_f16(a2, w2, acc[2][2], 0, 0, 0);
    acc[2][3] = __builtin_amdgcn_mfma_f32_16x16x32_f16(a2, w3, acc[2][3], 0, 0, 0);
    acc[3][0] = __builtin_amdgcn_mfma_f32_16x16x32_f16(a3, w0, acc[3][0], 0, 0, 0);
    acc[3][1] = __builtin_amdgcn_mfma_f32_16x16x32_f16(a3, w1, acc[3][1], 0, 0, 0);
    acc[3][2] = __builtin_amdgcn_mfma_f32_16x16x32_f16(a3, w2, acc[3][2], 0, 0, 0);
    acc[3][3] = __builtin_amdgcn_mfma_f32_16x16x32_f16(a3, w3, acc[3][3], 0, 0, 0);
  }

#pragma unroll
  for (int ct = 0; ct < 4; ct++) {
    const int co = w * 64 + ct * 16 + lr;
    const float bv = bias[co];
#pragma unroll
    for (int tt = 0; tt < 4; tt++) {
#pragma unroll
      for (int r = 0; r < 4; r++) {
        const int t = t0 + tt * 16 + (l >> 4) * 4 + r;
        if (t < T_) {
          float v = tanhf(acc[tt][ct][r] + bv);
          if constexpr (OUTF32)
            ((float*)yout)[((size_t)b * T_ + t) * H_ + co] = v;
          else
            ((_Float16*)yout)[((size_t)b * T_ + t) * H_ + co] = (_Float16)v;
        }
      }
    }
  }
}

// ---------------- W[b,t,s] = sum_h Wspec[b,t,h] * src_enc[b,s,h] --------
__global__ __launch_bounds__(256)
void einsum_ts(const float* __restrict__ A, const float* __restrict__ E,
               float* __restrict__ Wg)
{
  constexpr int GT = 128, GS = 64, KC = 16;
  __shared__ float As[KC][GT + 4];
  __shared__ float Bs[KC][GS + 4];
  const int b   = blockIdx.z;
  const int t0  = blockIdx.x * GT;
  const int s0  = blockIdx.y * GS;
  const int tid = threadIdx.x;
  const int tx  = tid & 15;
  const int ty  = tid >> 4;
  float4 acc[8];
#pragma unroll
  for (int i = 0; i < 8; i++) acc[i] = make_float4(0.f, 0.f, 0.f, 0.f);
  const float* Ab = A + (size_t)b * T_ * H_;
  const float* Eb = E + (size_t)b * S_ * H_;
  for (int kc = 0; kc < H_; kc += KC) {
#pragma unroll
    for (int r = 0; r < 2; r++) {
      int f4  = tid + 256 * r;
      int row = f4 >> 2;
      int c4  = f4 & 3;
      int t   = t0 + row;
      float4 v = make_float4(0, 0, 0, 0);
      if (t < T_) v = *(const float4*)&Ab[(size_t)t * H_ + kc + c4 * 4];
      As[c4*4+0][row] = v.x; As[c4*4+1][row] = v.y;
      As[c4*4+2][row] = v.z; As[c4*4+3][row] = v.w;
    }
    {
      int row = tid >> 2;
      int c4  = tid & 3;
      int s   = s0 + row;
      float4 v = make_float4(0, 0, 0, 0);
      if (s < S_) v = *(const float4*)&Eb[(size_t)s * H_ + kc + c4 * 4];
      Bs[c4*4+0][row] = v.x; Bs[c4*4+1][row] = v.y;
      Bs[c4*4+2][row] = v.z; Bs[c4*4+3][row] = v.w;
    }
    __syncthreads();
#pragma unroll
    for (int kk = 0; kk < KC; kk++) {
      float4 a0 = *(const float4*)&As[kk][ty * 8];
      float4 a1 = *(const float4*)&As[kk][ty * 8 + 4];
      float4 bb = *(const float4*)&Bs[kk][tx * 4];
      float av[8] = {a0.x, a0.y, a0.z, a0.w, a1.x, a1.y, a1.z, a1.w};
#pragma unroll
      for (int i = 0; i < 8; i++) {
        acc[i].x = fmaf(av[i], bb.x, acc[i].x);
        acc[i].y = fmaf(av[i], bb.y, acc[i].y);
        acc[i].z = fmaf(av[i], bb.z, acc[i].z);
        acc[i].w = fmaf(av[i], bb.w, acc[i].w);
      }
    }
    __syncthreads();
  }
  float* Wb = Wg + (size_t)b * T_ * S_;
  const int s = s0 + tx * 4;
#pragma unroll
  for (int i = 0; i < 8; i++) {
    int t = t0 + ty * 8 + i;
    if (t < T_ && s < S_) *(float4*)&Wb[(size_t)t * S_ + s] = acc[i];
  }
}

// ---------------- per-(b,s) column softmax stats over T ------------------
__global__ __launch_bounds__(256)
void softmax_stats(const float* __restrict__ Wg, float* __restrict__ statsOut)
{
  const int b  = blockIdx.y;
  const int tx = threadIdx.x & 63;
  const int ty = threadIdx.x >> 6;            // 0..3
  const int s  = blockIdx.x * 64 + tx;
  const bool act = (s < S_);
  float m = -1e30f, l = 0.f;
  if (act) {
    const float* col = Wg + (size_t)b * T_ * S_ + s;
#pragma unroll 4
    for (int t = ty; t < T_; t += 4) {
      float v  = col[(size_t)t * S_];
      float nm = fmaxf(m, v);
      l = l * __expf(m - nm) + __expf(v - nm);
      m = nm;
    }
  }
  __shared__ float rm[4][64], rl[4][64];
  rm[ty][tx] = m; rl[ty][tx] = l;
  __syncthreads();
  if (ty == 0 && act) {
    float M = rm[0][tx];
#pragma unroll
    for (int q = 1; q < 4; q++) M = fmaxf(M, rm[q][tx]);
    float L = 0.f;
#pragma unroll
    for (int q = 0; q < 4; q++) L += rl[q][tx] * __expf(rm[q][tx] - M);
    float* st = statsOut + (size_t)b * T_ * S_;
    st[s] = M + __logf(L);                    // single fused stat
  }
}

// ---------------- alignment normalize + mask premultiply -----------------
__global__ __launch_bounds__(256)
void norm_kernel(float* __restrict__ al,
                 const float* __restrict__ Mk,
                 const float* __restrict__ muStat,
                 float* __restrict__ Wdp)
{
  const int gid = blockIdx.x * 256 + threadIdx.x;
  if (gid >= NMU / 4) return;
  const int b   = gid / (T_ * S_ / 4);
  const int rem = gid - b * (T_ * S_ / 4);
  const int s4  = rem % (S_ / 4);
  const float4 st4 = *(const float4*)&muStat[(size_t)b * T_ * S_ + 4 * s4];
  float4 r = ((const float4*)al)[gid];
  float4 k = ((const float4*)Mk)[gid];
  float4 a;
  a.x = __expf(r.x - st4.x);
  a.y = __expf(r.y - st4.y);
  a.z = __expf(r.z - st4.z);
  a.w = __expf(r.w - st4.w);
  ((float4*)al)[gid]  = a;
  ((float4*)Wdp)[gid] = make_float4(a.x * k.x, a.y * k.y, a.z * k.z, a.w * k.w);
}

// ---------------- monotonic-alignment DP: skewed 4-wave pipeline ---------
// 1 block/batch, 5 waves: waves 0..3 each own a 100-col slice (2 cells/lane,
// lanes 0..49); wave 4 DMA-stages Wdp rows into a 16-row LDS ring. No
// barriers after init: producer->consumer via `ready` flag (counted vmcnt),
// wave->wave boundary values via LDS ring queues with per-wave counters
// (lgkmcnt(0) orders data before flag). Boundary shfl + queue reads for
// step t+1 are issued at the end of step t (latency hidden).
__device__ __forceinline__ float dpcell(float wv, float prev, float sft) {
  float d  = prev - sft;
  float e  = __expf(-fabsf(d));
  float lg = __logf(1.f + e);
  float mx = fmaxf(prev, sft);
  return wv + mx + lg;
}

__global__ __launch_bounds__(320, 1)
void dp_pipe(const float* __restrict__ Wdp,   // [B,T,S] = alignments * mask
             float* __restrict__ muOut)       // [B,T,S]
{
  __shared__ float ring[16 * S_];             // 25.6 KB
  __shared__ float bq[4][64];                 // boundary queues
  __shared__ int   qc[4];                     // queue counters (last step written)
  __shared__ int   prog[4];                   // consumer progress (for producer throttle)
  __shared__ int   ready;                     // last row landed in ring

  const int b   = blockIdx.x;
  const int tid = threadIdx.x;
  const int wv  = tid >> 6;                   // 0..4
  const int l   = tid & 63;

  if (tid == 0) { ready = -1; }
  if (tid < 4)  { qc[tid] = -1; prog[tid] = 0; }
  __syncthreads();

  const float* wb  = Wdp   + (size_t)b * T_ * S_;
  float*       mub = muOut + (size_t)b * T_ * S_;

  volatile int*   vready = &ready;
  volatile int*   vqc    = qc;
  volatile int*   vprog  = prog;
  volatile float* vbq    = &bq[0][0];

  if (wv == 4) {
    // ================= producer =================
    for (int r = 0; r < T_; ++r) {
      if (r >= 16) {
        // don't overwrite ring[r&15] (holds row r-16) until all consumed
        for (;;) {
          int p0 = vprog[0], p1 = vprog[1], p2 = vprog[2], p3 = vprog[3];
          int mn = min(min(p0, p1), min(p2, p3));
          if (mn >= r - 16) break;
        }
      }
      {
        const char* src_ = (const char*)(wb + (size_t)r * S_);
        char* dst_ = (char*)ring + ((r & 15) * 1600);
        __builtin_amdgcn_global_load_lds(
          (const __attribute__((address_space(1))) void*)(src_ + l * 16),
          (__attribute__((address_space(3))) void*)(dst_ + l * 16), 16, 0, 0);
        if (l < 36)
          __builtin_amdgcn_global_load_lds(
            (const __attribute__((address_space(1))) void*)(src_ + 1024 + l * 16),
            (__attribute__((address_space(3))) void*)(dst_ + 1024 + l * 16), 16, 0, 0);
      }
      if (r >= 8) {
        asm volatile("s_waitcnt vmcnt(16)" ::: "memory");   // rows <= r-8 landed
        *vready = r - 8;
      }
    }
    asm volatile("s_waitcnt vmcnt(0)" ::: "memory");
    *vready = T_ - 1;
    return;
  }

  // ================= consumers (waves 0..3) =================
  const int  lc   = (l < 50) ? l : 49;
  const int  scol = 100 * wv + 2 * lc;
  const bool act  = (l < 50);

  // wait row 0
  int lastReady = *vready;
  while (lastReady < 0) lastReady = *vready;
  float2 wj = *(float2*)&ring[(0 & 15) * S_ + scol];

  float m0 = wj.x + ((scol == 0) ? 0.f : NEGV);
  float m1 = wj.y + NEGV;                      // scol+1 >= 1 always
  if (act) *(float2*)&mub[scol] = make_float2(m0, m1);
  float shin = __shfl_up(m1, 1);
  if (l == 49) {
    vbq[wv * 64 + 0] = m1;
    asm volatile("s_waitcnt lgkmcnt(0)" ::: "memory");
    vqc[wv] = 0;
  }
  float bin = NEGV;
  if (wv > 0 && l == 0) {
    while (vqc[wv - 1] < 0) {}
    bin = vbq[(wv - 1) * 64 + 0];
  }
  // prefetch row 1
  if (lastReady < 1) { do { lastReady = *vready; } while (lastReady < 1); }
  wj = *(float2*)&ring[(1 & 15) * S_ + scol];

  for (int t = 1; ; ++t) {
    const float sft0 = (l == 0) ? bin : shin;
    const float p0 = m0, p1 = m1;
    m0 = dpcell(wj.x, p0, sft0);
    m1 = dpcell(wj.y, p1, p0);
    if (act) *(float2*)&mub[(size_t)t * S_ + scol] = make_float2(m0, m1);
    shin = __shfl_up(m1, 1);
    if (l == 49) vbq[wv * 64 + (t & 63)] = m1;   // entry t (for step t+1 of wave wv+1)
    if (t == T_ - 1) break;
    // prefetch row t+1
    if (lastReady < t + 1) { do { lastReady = *vready; } while (lastReady < t + 1); }
    wj = *(float2*)&ring[((t + 1) & 15) * S_ + scol];
    // boundary value for step t+1 (entry t of wave wv-1)
    if (wv > 0 && l == 0) {
      while (vqc[wv - 1] < t) {}
      bin = vbq[(wv - 1) * 64 + (t & 63)];
    }
    // publish queue entry t (data write above is older; order with lgkmcnt)
    if (l == 49) {
      asm volatile("s_waitcnt lgkmcnt(0)" ::: "memory");
      vqc[wv] = t;
    }
    if (l == 0 && (t & 3) == 3) vprog[wv] = t;
  }
  if (l == 0) vprog[wv] = T_ - 1;
}

// ---------------- pi from consecutive mu rows (fully parallel) -----------
__global__ __launch_bounds__(256)
void pi_kernel(const float* __restrict__ mu, float* __restrict__ pi)
{
  const int gid = blockIdx.x * 256 + threadIdx.x;
  if (gid >= NMU / 4) return;
  const int b   = gid / (T_ * S_ / 4);
  const int rem = gid - b * (T_ * S_ / 4);
  const int t   = rem / (S_ / 4);
  const int s4  = rem - t * (S_ / 4);
  float* wp = pi + (size_t)gid * 8;
  if (t == 0) {
    *(float4*)wp       = make_float4(1.f, 0.f, 1.f, 0.f);
    *(float4*)(wp + 4) = make_float4(1.f, 0.f, 1.f, 0.f);
    return;
  }
  const float* row = mu + (size_t)b * T_ * S_ + (size_t)(t - 1) * S_;
  float4 v = *(const float4*)&row[4 * s4];
  float left = (s4 == 0) ? NEGV : row[4 * s4 - 1];
  float pv[4] = {v.x, v.y, v.z, v.w};
  float sf[4] = {left, v.x, v.y, v.z};
  float p0[4], p1[4];
#pragma unroll
  for (int i = 0; i < 4; i++) {
    float d = pv[i] - sf[i];
    float e = __expf(-fabsf(d));
    float q = 1.f + e;
    float r;
    asm("v_rcp_f32 %0, %1" : "=v"(r) : "v"(q));
    float rr = (d >= 0.f) ? r : 1.f - r;
    p0[i] = rr; p1[i] = 1.f - rr;
  }
  *(float4*)wp       = make_float4(p0[0], p1[0], p0[1], p1[1]);
  *(float4*)(wp + 4) = make_float4(p0[2], p1[2], p0[3], p1[3]);
}

// -------------------------------------------------------------------------
extern "C" void kernel_launch(void* const* d_in, const int* in_sizes, int n_in,
                              void* d_out, int out_size, void* d_ws, size_t ws_size,
                              hipStream_t stream)
{
  (void)in_sizes; (void)n_in; (void)out_size; (void)d_ws; (void)ws_size;
  const float* x   = (const float*)d_in[0];
  const float* enc = (const float*)d_in[1];
  const float* msk = (const float*)d_in[2];
  const float* w1  = (const float*)d_in[3];
  const float* b1  = (const float*)d_in[4];
  const float* w2  = (const float*)d_in[5];
  const float* b2  = (const float*)d_in[6];
  const float* w3  = (const float*)d_in[7];
  const float* b3  = (const float*)d_in[8];

  float* out = (float*)d_out;
  float* mu  = out;                       // [B,T,S]
  float* pi  = out + NMU;                 // [B,T,S,2]
  float* al  = out + NMU + NPI;           // [B,T,S]
  float* wsp = out + NMU + NPI + NMU;     // [B,T,H] fp32

  // scratch inside pi region (pi written last, overwrites everything)
  float*     wdp = pi;                               // 25.6M floats
  _Float16*  h1  = (_Float16*)(pi + 26000000);       // 16.384M halves
  _Float16*  h2  = (_Float16*)(pi + 35000000);       // 16.384M halves
  _Float16*  wc1 = (_Float16*)(pi + 44000000);       // 256*480 halves
  _Float16*  wc2 = (_Float16*)(pi + 44100000);       // 256*1280 halves
  _Float16*  wc3 = (_Float16*)(pi + 44300000);       // 256*1280 halves

  hipLaunchKernelGGL(wprep, dim3((256*5*96 +255)/256), dim3(256), 0, stream, w1, wc1, C0_, 96);
  hipLaunchKernelGGL(wprep, dim3((256*5*256+255)/256), dim3(256), 0, stream, w2, wc2, H_, 256);
  hipLaunchKernelGGL(wprep, dim3((256*5*256+255)/256), dim3(256), 0, stream, w3, wc3, H_, 256);

  dim3 cgrid((T_ + 63) / 64, B_);
  hipLaunchKernelGGL((conv_mfma<C0_,  96, true,  false>), cgrid, dim3(256), 0, stream,
                     (const void*)x,  wc1, b1, (void*)h1);
  hipLaunchKernelGGL((conv_mfma<H_,  256, false, false>), cgrid, dim3(256), 0, stream,
                     (const void*)h1, wc2, b2, (void*)h2);
  hipLaunchKernelGGL((conv_mfma<H_,  256, false, true >), cgrid, dim3(256), 0, stream,
                     (const void*)h2, wc3, b3, (void*)wsp);

  hipLaunchKernelGGL(einsum_ts, dim3((T_ + 127) / 128, (S_ + 63) / 64, B_), dim3(256),
                     0, stream, wsp, enc, al);
  hipLaunchKernelGGL(softmax_stats, dim3((S_ + 63) / 64, B_), dim3(256), 0, stream, al, mu);
  hipLaunchKernelGGL(norm_kernel, dim3(NMU / 4 / 256), dim3(256), 0, stream, al, msk, mu, wdp);
  hipLaunchKernelGGL(dp_pipe, dim3(B_), dim3(320), 0, stream, wdp, mu);
  hipLaunchKernelGGL(pi_kernel, dim3(NMU / 4 / 256), dim3(256), 0, stream, mu, pi);
}

// Round 11
// 1487.280 us; speedup vs baseline: 1.2949x; 1.2949x over previous
//
#include <hip/hip_runtime.h>
#include <hip/hip_bf16.h>

#define B_ 32
#define T_ 2000
#define S_ 400
#define C0_ 80
#define H_ 256

static constexpr float NEGV = -1e9f;
static constexpr int NMU  = B_ * T_ * S_;       // 25,600,000
static constexpr int NPI  = 2 * NMU;            // 51,200,000

typedef _Float16 f16x8 __attribute__((ext_vector_type(8)));
typedef float    f32x4 __attribute__((ext_vector_type(4)));

// ---------------- weight repack: wcat[co][k*CPAD+ci] = w[k][ci][co] ------
__global__ __launch_bounds__(256)
void wprep(const float* __restrict__ w, _Float16* __restrict__ wcat,
           int CIN, int CPAD)
{
  const int tot = 256 * 5 * CPAD;
  int idx = blockIdx.x * 256 + threadIdx.x;
  if (idx >= tot) return;
  int co  = idx / (5 * CPAD);
  int rem = idx - co * (5 * CPAD);
  int k   = rem / CPAD;
  int ci  = rem - k * CPAD;
  float v = (ci < CIN) ? w[((size_t)k * CIN + ci) * H_ + co] : 0.f;
  wcat[idx] = (_Float16)v;
}

// ---------------- conv1d (K=5, SAME) + bias + tanh via f16 MFMA ----------
template<int CIN, int CPAD, bool INF32, bool OUTF32>
__global__ __launch_bounds__(256)
void conv_mfma(const void* __restrict__ xin, const _Float16* __restrict__ wcat,
               const float* __restrict__ bias, void* __restrict__ yout)
{
  constexpr int KK  = 5 * CPAD;      // 480 / 1280
  constexpr int NS  = KK / 32;       // 15 / 40
  constexpr int STR = CPAD + 8;      // LDS row stride
  __shared__ _Float16 xs[68 * STR];
  const int b   = blockIdx.y;
  const int t0  = blockIdx.x * 64;
  const int tid = threadIdx.x;
  const int w   = tid >> 6;
  const int l   = tid & 63;

  if constexpr (INF32) {
    const float* xb = (const float*)xin + (size_t)b * T_ * CIN;
    constexpr int NG = CPAD / 4;
    for (int idx = tid; idx < 68 * NG; idx += 256) {
      int j = idx / NG, g = idx - j * NG;
      int t = t0 - 2 + j;
      int c = g * 4;
      float4 v = make_float4(0.f, 0.f, 0.f, 0.f);
      if (t >= 0 && t < T_ && c < CIN) v = *(const float4*)&xb[(size_t)t * CIN + c];
      _Float16* d = &xs[j * STR + c];
      d[0] = (_Float16)v.x; d[1] = (_Float16)v.y;
      d[2] = (_Float16)v.z; d[3] = (_Float16)v.w;
    }
  } else {
    const _Float16* xb = (const _Float16*)xin + (size_t)b * T_ * CIN;
    constexpr int NG = CPAD / 8;
    for (int idx = tid; idx < 68 * NG; idx += 256) {
      int j = idx / NG, g = idx - j * NG;
      int t = t0 - 2 + j;
      f16x8 v = {(_Float16)0,(_Float16)0,(_Float16)0,(_Float16)0,
                 (_Float16)0,(_Float16)0,(_Float16)0,(_Float16)0};
      if (t >= 0 && t < T_) v = *(const f16x8*)&xb[(size_t)t * CIN + g * 8];
      *(f16x8*)&xs[j * STR + g * 8] = v;
    }
  }
  __syncthreads();

  const int lr = l & 15;
  const int lk = (l >> 4) * 8;

  f32x4 acc[4][4];
  const f32x4 zz = {0.f, 0.f, 0.f, 0.f};
#pragma unroll
  for (int i = 0; i < 4; i++)
#pragma unroll
    for (int j = 0; j < 4; j++) acc[i][j] = zz;

  const _Float16* wbase = wcat + (size_t)(w * 64 + lr) * KK + lk;

  for (int kk = 0; kk < NS; kk++) {
    const int p  = kk * 32;
    const int k  = p / CPAD;
    const int ci = p - k * CPAD;
    f16x8 a0 = *(const f16x8*)&xs[( 0 + lr + k) * STR + ci + lk];
    f16x8 a1 = *(const f16x8*)&xs[(16 + lr + k) * STR + ci + lk];
    f16x8 a2 = *(const f16x8*)&xs[(32 + lr + k) * STR + ci + lk];
    f16x8 a3 = *(const f16x8*)&xs[(48 + lr + k) * STR + ci + lk];
    f16x8 w0 = *(const f16x8*)&wbase[(size_t)( 0) * KK + p];
    f16x8 w1 = *(const f16x8*)&wbase[(size_t)(16) * KK + p];
    f16x8 w2 = *(const f16x8*)&wbase[(size_t)(32) * KK + p];
    f16x8 w3 = *(const f16x8*)&wbase[(size_t)(48) * KK + p];
    acc[0][0] = __builtin_amdgcn_mfma_f32_16x16x32_f16(a0, w0, acc[0][0], 0, 0, 0);
    acc[0][1] = __builtin_amdgcn_mfma_f32_16x16x32_f16(a0, w1, acc[0][1], 0, 0, 0);
    acc[0][2] = __builtin_amdgcn_mfma_f32_16x16x32_f16(a0, w2, acc[0][2], 0, 0, 0);
    acc[0][3] = __builtin_amdgcn_mfma_f32_16x16x32_f16(a0, w3, acc[0][3], 0, 0, 0);
    acc[1][0] = __builtin_amdgcn_mfma_f32_16x16x32_f16(a1, w0, acc[1][0], 0, 0, 0);
    acc[1][1] = __builtin_amdgcn_mfma_f32_16x16x32_f16(a1, w1, acc[1][1], 0, 0, 0);
    acc[1][2] = __builtin_amdgcn_mfma_f32_16x16x32_f16(a1, w2, acc[1][2], 0, 0, 0);
    acc[1][3] = __builtin_amdgcn_mfma_f32_16x16x32_f16(a1, w3, acc[1][3], 0, 0, 0);
    acc[2][0] = __builtin_amdgcn_mfma_f32_16x16x32_f16(a2, w0, acc[2][0], 0, 0, 0);
    acc[2][1] = __builtin_amdgcn_mfma_f32_16x16x32_f16(a2, w1, acc[2][1], 0, 0, 0);
    acc[2][2] = __builtin_amdgcn_mfma_f32_16x16x32_f16(a2, w2, acc[2][2], 0, 0, 0);
    acc[2][3] = __builtin_amdgcn_mfma_f32_16x16x32_f16(a2, w3, acc[2][3], 0, 0, 0);
    acc[3][0] = __builtin_amdgcn_mfma_f32_16x16x32_f16(a3, w0, acc[3][0], 0, 0, 0);
    acc[3][1] = __builtin_amdgcn_mfma_f32_16x16x32_f16(a3, w1, acc[3][1], 0, 0, 0);
    acc[3][2] = __builtin_amdgcn_mfma_f32_16x16x32_f16(a3, w2, acc[3][2], 0, 0, 0);
    acc[3][3] = __builtin_amdgcn_mfma_f32_16x16x32_f16(a3, w3, acc[3][3], 0, 0, 0);
  }

#pragma unroll
  for (int ct = 0; ct < 4; ct++) {
    const int co = w * 64 + ct * 16 + lr;
    const float bv = bias[co];
#pragma unroll
    for (int tt = 0; tt < 4; tt++) {
#pragma unroll
      for (int r = 0; r < 4; r++) {
        const int t = t0 + tt * 16 + (l >> 4) * 4 + r;
        if (t < T_) {
          float v = tanhf(acc[tt][ct][r] + bv);
          if constexpr (OUTF32)
            ((float*)yout)[((size_t)b * T_ + t) * H_ + co] = v;
          else
            ((_Float16*)yout)[((size_t)b * T_ + t) * H_ + co] = (_Float16)v;
        }
      }
    }
  }
}

// ---------------- W[b,t,s] = sum_h Wspec[b,t,h] * src_enc[b,s,h] --------
__global__ __launch_bounds__(256)
void einsum_ts(const float* __restrict__ A, const float* __restrict__ E,
               float* __restrict__ Wg)
{
  constexpr int GT = 128, GS = 64, KC = 16;
  __shared__ float As[KC][GT + 4];
  __shared__ float Bs[KC][GS + 4];
  const int b   = blockIdx.z;
  const int t0  = blockIdx.x * GT;
  const int s0  = blockIdx.y * GS;
  const int tid = threadIdx.x;
  const int tx  = tid & 15;
  const int ty  = tid >> 4;
  float4 acc[8];
#pragma unroll
  for (int i = 0; i < 8; i++) acc[i] = make_float4(0.f, 0.f, 0.f, 0.f);
  const float* Ab = A + (size_t)b * T_ * H_;
  const float* Eb = E + (size_t)b * S_ * H_;
  for (int kc = 0; kc < H_; kc += KC) {
#pragma unroll
    for (int r = 0; r < 2; r++) {
      int f4  = tid + 256 * r;
      int row = f4 >> 2;
      int c4  = f4 & 3;
      int t   = t0 + row;
      float4 v = make_float4(0, 0, 0, 0);
      if (t < T_) v = *(const float4*)&Ab[(size_t)t * H_ + kc + c4 * 4];
      As[c4*4+0][row] = v.x; As[c4*4+1][row] = v.y;
      As[c4*4+2][row] = v.z; As[c4*4+3][row] = v.w;
    }
    {
      int row = tid >> 2;
      int c4  = tid & 3;
      int s   = s0 + row;
      float4 v = make_float4(0, 0, 0, 0);
      if (s < S_) v = *(const float4*)&Eb[(size_t)s * H_ + kc + c4 * 4];
      Bs[c4*4+0][row] = v.x; Bs[c4*4+1][row] = v.y;
      Bs[c4*4+2][row] = v.z; Bs[c4*4+3][row] = v.w;
    }
    __syncthreads();
#pragma unroll
    for (int kk = 0; kk < KC; kk++) {
      float4 a0 = *(const float4*)&As[kk][ty * 8];
      float4 a1 = *(const float4*)&As[kk][ty * 8 + 4];
      float4 bb = *(const float4*)&Bs[kk][tx * 4];
      float av[8] = {a0.x, a0.y, a0.z, a0.w, a1.x, a1.y, a1.z, a1.w};
#pragma unroll
      for (int i = 0; i < 8; i++) {
        acc[i].x = fmaf(av[i], bb.x, acc[i].x);
        acc[i].y = fmaf(av[i], bb.y, acc[i].y);
        acc[i].z = fmaf(av[i], bb.z, acc[i].z);
        acc[i].w = fmaf(av[i], bb.w, acc[i].w);
      }
    }
    __syncthreads();
  }
  float* Wb = Wg + (size_t)b * T_ * S_;
  const int s = s0 + tx * 4;
#pragma unroll
  for (int i = 0; i < 8; i++) {
    int t = t0 + ty * 8 + i;
    if (t < T_ && s < S_) *(float4*)&Wb[(size_t)t * S_ + s] = acc[i];
  }
}

// ---------------- per-(b,s) column softmax stats over T ------------------
__global__ __launch_bounds__(256)
void softmax_stats(const float* __restrict__ Wg, float* __restrict__ statsOut)
{
  const int b  = blockIdx.y;
  const int tx = threadIdx.x & 63;
  const int ty = threadIdx.x >> 6;            // 0..3
  const int s  = blockIdx.x * 64 + tx;
  const bool act = (s < S_);
  float m = -1e30f, l = 0.f;
  if (act) {
    const float* col = Wg + (size_t)b * T_ * S_ + s;
#pragma unroll 4
    for (int t = ty; t < T_; t += 4) {
      float v  = col[(size_t)t * S_];
      float nm = fmaxf(m, v);
      l = l * __expf(m - nm) + __expf(v - nm);
      m = nm;
    }
  }
  __shared__ float rm[4][64], rl[4][64];
  rm[ty][tx] = m; rl[ty][tx] = l;
  __syncthreads();
  if (ty == 0 && act) {
    float M = rm[0][tx];
#pragma unroll
    for (int q = 1; q < 4; q++) M = fmaxf(M, rm[q][tx]);
    float L = 0.f;
#pragma unroll
    for (int q = 0; q < 4; q++) L += rl[q][tx] * __expf(rm[q][tx] - M);
    float* st = statsOut + (size_t)b * T_ * S_;
    st[s] = M + __logf(L);                    // single fused stat
  }
}

// ---------------- alignment normalize + mask premultiply -----------------
__global__ __launch_bounds__(256)
void norm_kernel(float* __restrict__ al,
                 const float* __restrict__ Mk,
                 const float* __restrict__ muStat,
                 float* __restrict__ Wdp)
{
  const int gid = blockIdx.x * 256 + threadIdx.x;
  if (gid >= NMU / 4) return;
  const int b   = gid / (T_ * S_ / 4);
  const int rem = gid - b * (T_ * S_ / 4);
  const int s4  = rem % (S_ / 4);
  const float4 st4 = *(const float4*)&muStat[(size_t)b * T_ * S_ + 4 * s4];
  float4 r = ((const float4*)al)[gid];
  float4 k = ((const float4*)Mk)[gid];
  float4 a;
  a.x = __expf(r.x - st4.x);
  a.y = __expf(r.y - st4.y);
  a.z = __expf(r.z - st4.z);
  a.w = __expf(r.w - st4.w);
  ((float4*)al)[gid]  = a;
  ((float4*)Wdp)[gid] = make_float4(a.x * k.x, a.y * k.y, a.z * k.z, a.w * k.w);
}

// ---------------- monotonic-alignment DP: mu only, FENCED prefetch -------
// r4 structure + asm memory fences after each prefetch load: the empty
// memory-clobber asm pins the load's EMISSION point (compiler cannot sink
// it to the use 4 steps later), while the backend still inserts exact
// counted vmcnt before first use. Lane l owns s=8l..8l+7, one __shfl_up
// per step, 32 blocks x 1 wave.
__global__ __launch_bounds__(64, 1)
void dp_mu(const float* __restrict__ Wdp, float* __restrict__ muOut)
{
  const int b = blockIdx.x;
  const int l = threadIdx.x;
  const int s0raw = l * 8;
  const bool act = (s0raw < S_);
  const int c0 = act ? s0raw : (S_ - 8);

  const float* wb  = Wdp   + (size_t)b * T_ * S_;
  float*       mub = muOut + (size_t)b * T_ * S_;

  float m[8];
  {
    float4 lo = *(const float4*)&wb[c0];
    float4 hi = *(const float4*)&wb[c0 + 4];
    float w0[8] = {lo.x,lo.y,lo.z,lo.w,hi.x,hi.y,hi.z,hi.w};
#pragma unroll
    for (int j = 0; j < 8; j++) m[j] = w0[j] + ((c0 + j) == 0 ? 0.f : NEGV);
    if (act) {
      *(float4*)&mub[c0]     = make_float4(m[0],m[1],m[2],m[3]);
      *(float4*)&mub[c0 + 4] = make_float4(m[4],m[5],m[6],m[7]);
    }
  }

  float4 wL[4], wH[4];

#define LOADW(slot, row)                                                    \
  { const float* r_ = wb + (size_t)(row) * S_ + c0;                         \
    wL[slot] = *(const float4*)r_;  wH[slot] = *(const float4*)(r_ + 4);    \
    asm volatile("" ::: "memory"); }

#define DPSTEP(slot, t, prow, doPF)                                         \
  { float wj[8] = {wL[slot].x,wL[slot].y,wL[slot].z,wL[slot].w,             \
                   wH[slot].x,wH[slot].y,wH[slot].z,wH[slot].w};            \
    if (doPF) LOADW(slot, prow)                                             \
    float sh = __shfl_up(m[7], 1);                                          \
    if (l == 0) sh = NEGV;                                                  \
    _Pragma("unroll")                                                       \
    for (int j = 7; j >= 0; j--) {                                          \
      float prev = m[j];                                                    \
      float sft  = (j == 0) ? sh : m[j - 1];                                \
      float d    = prev - sft;                                              \
      float e    = __expf(-fabsf(d));                                       \
      float lg   = __logf(1.f + e);                                         \
      float hi   = fmaxf(prev, sft);                                        \
      m[j] = wj[j] + hi + lg;                                               \
    }                                                                       \
    if (act) {                                                              \
      float* wm_ = mub + (size_t)(t) * S_ + c0;                             \
      *(float4*)wm_       = make_float4(m[0],m[1],m[2],m[3]);               \
      *(float4*)(wm_ + 4) = make_float4(m[4],m[5],m[6],m[7]);               \
    } }

  LOADW(0, 1) LOADW(1, 2) LOADW(2, 3) LOADW(3, 4)

  int t0 = 1;
  for (; t0 + 7 <= T_ - 1; t0 += 4) {
    DPSTEP(0, t0 + 0, t0 + 4, true)
    DPSTEP(1, t0 + 1, t0 + 5, true)
    DPSTEP(2, t0 + 2, t0 + 6, true)
    DPSTEP(3, t0 + 3, t0 + 7, true)
  }
  DPSTEP(0, 1993, 1997, true)
  DPSTEP(1, 1994, 1998, true)
  DPSTEP(2, 1995, 1999, true)
  DPSTEP(3, 1996, 0, false)
  DPSTEP(0, 1997, 0, false)
  DPSTEP(1, 1998, 0, false)
  DPSTEP(2, 1999, 0, false)

#undef LOADW
#undef DPSTEP
}

// ---------------- pi from consecutive mu rows (fully parallel) -----------
__global__ __launch_bounds__(256)
void pi_kernel(const float* __restrict__ mu, float* __restrict__ pi)
{
  const int gid = blockIdx.x * 256 + threadIdx.x;
  if (gid >= NMU / 4) return;
  const int b   = gid / (T_ * S_ / 4);
  const int rem = gid - b * (T_ * S_ / 4);
  const int t   = rem / (S_ / 4);
  const int s4  = rem - t * (S_ / 4);
  float* wp = pi + (size_t)gid * 8;
  if (t == 0) {
    *(float4*)wp       = make_float4(1.f, 0.f, 1.f, 0.f);
    *(float4*)(wp + 4) = make_float4(1.f, 0.f, 1.f, 0.f);
    return;
  }
  const float* row = mu + (size_t)b * T_ * S_ + (size_t)(t - 1) * S_;
  float4 v = *(const float4*)&row[4 * s4];
  float left = (s4 == 0) ? NEGV : row[4 * s4 - 1];
  float pv[4] = {v.x, v.y, v.z, v.w};
  float sf[4] = {left, v.x, v.y, v.z};
  float p0[4], p1[4];
#pragma unroll
  for (int i = 0; i < 4; i++) {
    float d = pv[i] - sf[i];
    float e = __expf(-fabsf(d));
    float q = 1.f + e;
    float r;
    asm("v_rcp_f32 %0, %1" : "=v"(r) : "v"(q));
    float rr = (d >= 0.f) ? r : 1.f - r;
    p0[i] = rr; p1[i] = 1.f - rr;
  }
  *(float4*)wp       = make_float4(p0[0], p1[0], p0[1], p1[1]);
  *(float4*)(wp + 4) = make_float4(p0[2], p1[2], p0[3], p1[3]);
}

// -------------------------------------------------------------------------
extern "C" void kernel_launch(void* const* d_in, const int* in_sizes, int n_in,
                              void* d_out, int out_size, void* d_ws, size_t ws_size,
                              hipStream_t stream)
{
  (void)in_sizes; (void)n_in; (void)out_size; (void)d_ws; (void)ws_size;
  const float* x   = (const float*)d_in[0];
  const float* enc = (const float*)d_in[1];
  const float* msk = (const float*)d_in[2];
  const float* w1  = (const float*)d_in[3];
  const float* b1  = (const float*)d_in[4];
  const float* w2  = (const float*)d_in[5];
  const float* b2  = (const float*)d_in[6];
  const float* w3  = (const float*)d_in[7];
  const float* b3  = (const float*)d_in[8];

  float* out = (float*)d_out;
  float* mu  = out;                       // [B,T,S]
  float* pi  = out + NMU;                 // [B,T,S,2]
  float* al  = out + NMU + NPI;           // [B,T,S]
  float* wsp = out + NMU + NPI + NMU;     // [B,T,H] fp32

  // scratch inside pi region (pi written last, overwrites everything)
  float*     wdp = pi;                               // 25.6M floats
  _Float16*  h1  = (_Float16*)(pi + 26000000);       // 16.384M halves
  _Float16*  h2  = (_Float16*)(pi + 35000000);       // 16.384M halves
  _Float16*  wc1 = (_Float16*)(pi + 44000000);       // 256*480 halves
  _Float16*  wc2 = (_Float16*)(pi + 44100000);       // 256*1280 halves
  _Float16*  wc3 = (_Float16*)(pi + 44300000);       // 256*1280 halves

  hipLaunchKernelGGL(wprep, dim3((256*5*96 +255)/256), dim3(256), 0, stream, w1, wc1, C0_, 96);
  hipLaunchKernelGGL(wprep, dim3((256*5*256+255)/256), dim3(256), 0, stream, w2, wc2, H_, 256);
  hipLaunchKernelGGL(wprep, dim3((256*5*256+255)/256), dim3(256), 0, stream, w3, wc3, H_, 256);

  dim3 cgrid((T_ + 63) / 64, B_);
  hipLaunchKernelGGL((conv_mfma<C0_,  96, true,  false>), cgrid, dim3(256), 0, stream,
                     (const void*)x,  wc1, b1, (void*)h1);
  hipLaunchKernelGGL((conv_mfma<H_,  256, false, false>), cgrid, dim3(256), 0, stream,
                     (const void*)h1, wc2, b2, (void*)h2);
  hipLaunchKernelGGL((conv_mfma<H_,  256, false, true >), cgrid, dim3(256), 0, stream,
                     (const void*)h2, wc3, b3, (void*)wsp);

  hipLaunchKernelGGL(einsum_ts, dim3((T_ + 127) / 128, (S_ + 63) / 64, B_), dim3(256),
                     0, stream, wsp, enc, al);
  hipLaunchKernelGGL(softmax_stats, dim3((S_ + 63) / 64, B_), dim3(256), 0, stream, al, mu);
  hipLaunchKernelGGL(norm_kernel, dim3(NMU / 4 / 256), dim3(256), 0, stream, al, msk, mu, wdp);
  hipLaunchKernelGGL(dp_mu, dim3(B_), dim3(64), 0, stream, wdp, mu);
  hipLaunchKernelGGL(pi_kernel, dim3(NMU / 4 / 256), dim3(256), 0, stream, mu, pi);
}